// Round 1
// baseline (2580.369 us; speedup 1.0000x reference)
//
#include <hip/hip_runtime.h>
#include <hip/hip_bf16.h>

// ButterFlyNet2D forward, fp32 baseline.
// Layer k output layout: [B=256][CH_k][S_k][S_k] with CH_k = 4^(k+1)*16, S_k = 2^(5-k).
// Every intermediate buffer = 256*65536 = 16,777,216 floats (64 MiB). Two ping-pong bufs in d_ws.

// ---------------- Layer 0: split -> conv(4->64,2x2) -> relu -> wrap-pad -> pool ----------------
__global__ __launch_bounds__(256) void k_layer0(
    const float* __restrict__ x, const float* __restrict__ W0,
    const float* __restrict__ b0, float* __restrict__ out) {
  __shared__ __align__(16) float xs[64 * 64];
  const int b = blockIdx.x;
  const float* xb = x + (size_t)b * 4096;
  for (int i = threadIdx.x; i < 1024; i += 256)
    ((float4*)xs)[i] = ((const float4*)xb)[i];
  __syncthreads();
  const int oc = threadIdx.x & 63;
  const int wv = threadIdx.x >> 6;
  // weights for ic=0 (relu(x)) and ic=1 (relu(-x)); ic=2,3 inputs are identically 0
  float w[2][2][2];
#pragma unroll
  for (int ic = 0; ic < 2; ic++)
#pragma unroll
    for (int kh = 0; kh < 2; kh++)
#pragma unroll
      for (int kw = 0; kw < 2; kw++)
        w[ic][kh][kw] = W0[((oc * 4 + ic) * 2 + kh) * 2 + kw];
  const float bias = b0[oc];
  float* ob = out + (size_t)b * 65536 + (size_t)oc * 1024;
  for (int slot = wv; slot < 1024; slot += 4) {  // all 64 lanes share slot -> broadcast LDS reads
    const int ph = slot >> 5, pw = slot & 31;
    float acc = 0.f;
#pragma unroll
    for (int dy = 0; dy < 2; dy++) {
      int r = 2 * ph + dy; if (r == 63) r = 0;   // wrap-pad: padded row 63 == conv row 0
#pragma unroll
      for (int dx = 0; dx < 2; dx++) {
        int q = 2 * pw + dx; if (q == 63) q = 0;
        float s = bias;
#pragma unroll
        for (int kh = 0; kh < 2; kh++)
#pragma unroll
          for (int kw = 0; kw < 2; kw++) {
            float xv = xs[(r + kh) * 64 + (q + kw)];
            s += w[0][kh][kw] * fmaxf(xv, 0.f) + w[1][kh][kw] * fmaxf(-xv, 0.f);
          }
        acc += fmaxf(s, 0.f);
      }
    }
    ob[slot] = 0.25f * acc;
  }
}

// ---------------- Recursion layers 1..5 ----------------
// Grouped conv 16->64 per group (2x2 VALID) + bias + relu + wrap-pad + pool + butterfly channel permute.
// Block: (gi, batch-chunk[, ph-half]). Lane = within-group output channel (64).
// All lanes share the slot -> input LDS reads are same-address broadcasts (no bank conflicts).
template <int S_IN, int G, int BPB, int PSPLIT>
__global__ __launch_bounds__(256) void k_layer(
    const float* __restrict__ yin, const float* __restrict__ W,
    const float* __restrict__ Bv, float* __restrict__ yout) {
  constexpr int NB = G * G;
  constexpr int S_OUT = S_IN / 2;
  constexpr int PH_B = S_OUT / PSPLIT;                // ph rows handled per block
  constexpr int ROWS = (PSPLIT == 1) ? S_IN : 19;     // staged rows per (bi, ic)
  constexpr int INPG = 16 * ROWS * S_IN;              // staged floats per (bi)
  constexpr int INPG_FULL = 16 * S_IN * S_IN;         // floats per (b,gi) in global
  __shared__ __align__(16) float wsm[64 * 65];        // stride 65: conflict-free lane reads
  __shared__ __align__(16) float ins[BPB * INPG];
  const int gi = blockIdx.x;
  const int bc = blockIdx.y;
  const int p0 = (PSPLIT == 1) ? 0 : blockIdx.z * PH_B;
  const int tid = threadIdx.x;

  // stage weights [64][16*4] -> padded stride 65
  const float* wsrc = W + (size_t)gi * 4096;
  for (int i = tid; i < 4096; i += 256) wsm[(i >> 6) * 65 + (i & 63)] = wsrc[i];

  // stage input
  if (PSPLIT == 1) {
    constexpr int N4 = BPB * INPG / 4;
    for (int i = tid; i < N4; i += 256) {
      int bi = i / (INPG / 4), rem = i % (INPG / 4);
      *(float4*)&ins[i * 4] =
          *(const float4*)(yin + ((size_t)(bc * BPB + bi) * NB + gi) * INPG_FULL + rem * 4);
    }
  } else {
    // 19 staged rows: lr 0..16 -> global rows 2*p0+lr (clamped), lr 17,18 -> rows 0,1 (wrap)
    constexpr int N4 = BPB * INPG / 4;
    for (int i = tid; i < N4; i += 256) {
      int bi = i / (INPG / 4), rem = i % (INPG / 4);
      int ic = rem / (ROWS * S_IN / 4);
      int rem2 = rem % (ROWS * S_IN / 4);
      int lr = rem2 / (S_IN / 4);
      int c4 = rem2 % (S_IN / 4);
      int t = 2 * p0 + lr;
      int gr = (lr <= 16) ? (t < S_IN - 1 ? t : S_IN - 1) : (lr - 17);
      *(float4*)&ins[i * 4] =
          *(const float4*)(yin + ((size_t)(bc * BPB + bi) * NB + gi) * INPG_FULL +
                           (ic * S_IN + gr) * S_IN + c4 * 4);
    }
  }
  __syncthreads();

  const int oc = tid & 63;
  const int wv = tid >> 6;
  float wr[16][2][2];
#pragma unroll
  for (int ic = 0; ic < 16; ic++)
#pragma unroll
    for (int k = 0; k < 4; k++)
      wr[ic][k >> 1][k & 1] = wsm[oc * 65 + ic * 4 + k];
  const float breg = Bv[(size_t)gi * 64 + oc];

  // butterfly permute: (A_y, A_x, y_loc, x_loc, c) -> (((A_y*2+y_loc)*G + A_x)*2 + x_loc)*16 + c
  const int A_y = gi / G, A_x = gi % G;
  const int och = (((A_y * 2 + (oc >> 5)) * G + A_x) * 2 + ((oc >> 4) & 1)) * 16 + (oc & 15);

  constexpr int SLOTS = BPB * PH_B * S_OUT;
  for (int slot = wv; slot < SLOTS; slot += 4) {
    const int bi = slot / (PH_B * S_OUT);
    const int sp = slot % (PH_B * S_OUT);
    const int ph = p0 + sp / S_OUT;
    const int pw = sp % S_OUT;
    const float* inb = ins + bi * INPG;
    const int qL = 2 * pw;                       // conv col q0 (aligned)
    const bool wrapc = (pw == S_OUT - 1);        // q1 wraps to col 0
    const int qR = wrapc ? 0 : 2 * pw + 2;       // aligned companion load
    float acc = 0.f;
#pragma unroll
    for (int dy = 0; dy < 2; dy++) {
      int rc = 2 * ph + dy;
      if (rc == S_IN - 1) rc = 0;                // wrap-pad row
      const int lr = (PSPLIT == 1) ? rc : ((rc >= 2 * p0) ? rc - 2 * p0 : 17 + rc);
      float s0 = breg, s1 = breg;
      if (!wrapc) {
#pragma unroll
        for (int ic = 0; ic < 16; ic++) {
#pragma unroll
          for (int kh = 0; kh < 2; kh++) {
            const float* row = inb + (ic * ROWS + lr + kh) * S_IN;
            float2 L = *(const float2*)(row + qL);   // cols q0, q0+1
            float2 R = *(const float2*)(row + qR);   // cols q0+2, q0+3
            s0 += L.x * wr[ic][kh][0] + L.y * wr[ic][kh][1];
            s1 += L.y * wr[ic][kh][0] + R.x * wr[ic][kh][1];
          }
        }
      } else {
#pragma unroll
        for (int ic = 0; ic < 16; ic++) {
#pragma unroll
          for (int kh = 0; kh < 2; kh++) {
            const float* row = inb + (ic * ROWS + lr + kh) * S_IN;
            float2 L = *(const float2*)(row + qL);   // cols S_IN-2, S_IN-1
            float2 R = *(const float2*)(row + qR);   // cols 0, 1 (wrap)
            s0 += L.x * wr[ic][kh][0] + L.y * wr[ic][kh][1];
            s1 += R.x * wr[ic][kh][0] + R.y * wr[ic][kh][1];
          }
        }
      }
      acc += fmaxf(s0, 0.f) + fmaxf(s1, 0.f);
    }
    const int b = bc * BPB + bi;
    yout[((size_t)b * (NB * 64) + och) * (S_OUT * S_OUT) + (ph * S_OUT + pw)] = 0.25f * acc;
  }
}

// ---------------- FT layer: per-block 16->4 contraction + real/imag ----------------
__global__ __launch_bounds__(256) void k_ft(
    const float* __restrict__ v, const float* __restrict__ Wft,
    const float* __restrict__ bft, float* __restrict__ out) {
  const int idx = blockIdx.x * 256 + threadIdx.x;
  const int b = idx >> 12;
  const int n = idx & 4095;
  const float4* vp = (const float4*)(v + ((size_t)b * 4096 + n) * 16);
  float4 v0 = vp[0], v1 = vp[1], v2 = vp[2], v3 = vp[3];
  const float4* wp = (const float4*)(Wft + (size_t)n * 64);
  float f[4];
#pragma unroll
  for (int o = 0; o < 4; o++) {
    float4 w0 = wp[o * 4 + 0], w1 = wp[o * 4 + 1], w2 = wp[o * 4 + 2], w3 = wp[o * 4 + 3];
    f[o] = bft[n * 4 + o]
         + v0.x * w0.x + v0.y * w0.y + v0.z * w0.z + v0.w * w0.w
         + v1.x * w1.x + v1.y * w1.y + v1.z * w1.z + v1.w * w1.w
         + v2.x * w2.x + v2.y * w2.y + v2.z * w2.z + v2.w * w2.w
         + v3.x * w3.x + v3.y * w3.y + v3.z * w3.z + v3.w * w3.w;
  }
  out[(size_t)b * 8192 + n] = f[0] - f[1];          // real
  out[(size_t)b * 8192 + 4096 + n] = f[2] - f[3];   // imag
}

extern "C" void kernel_launch(void* const* d_in, const int* in_sizes, int n_in,
                              void* d_out, int out_size, void* d_ws, size_t ws_size,
                              hipStream_t stream) {
  const float* x   = (const float*)d_in[0];
  const float* W0  = (const float*)d_in[1];
  const float* b0  = (const float*)d_in[2];
  const float* Wft = (const float*)d_in[3];
  const float* bft = (const float*)d_in[4];
  const float* W1 = (const float*)d_in[5];  const float* b1 = (const float*)d_in[6];
  const float* W2 = (const float*)d_in[7];  const float* b2 = (const float*)d_in[8];
  const float* W3 = (const float*)d_in[9];  const float* b3 = (const float*)d_in[10];
  const float* W4 = (const float*)d_in[11]; const float* b4 = (const float*)d_in[12];
  const float* W5 = (const float*)d_in[13]; const float* b5 = (const float*)d_in[14];

  float* buf0 = (float*)d_ws;
  float* buf1 = buf0 + (size_t)16777216;  // 64 MiB each; ws must hold 128 MiB

  k_layer0<<<256, 256, 0, stream>>>(x, W0, b0, buf0);
  // Layer 1: S_IN=32, G=2 (4 groups), 1 image/block, ph split in 2
  k_layer<32, 2, 1, 2><<<dim3(4, 256, 2), 256, 0, stream>>>(buf0, W1, b1, buf1);
  // Layer 2: S_IN=16, G=4 (16 groups), 2 images/block
  k_layer<16, 4, 2, 1><<<dim3(16, 128, 1), 256, 0, stream>>>(buf1, W2, b2, buf0);
  // Layer 3: S_IN=8, G=8 (64 groups), 8 images/block
  k_layer<8, 8, 8, 1><<<dim3(64, 32, 1), 256, 0, stream>>>(buf0, W3, b3, buf1);
  // Layer 4: S_IN=4, G=16 (256 groups), 32 images/block
  k_layer<4, 16, 32, 1><<<dim3(256, 8, 1), 256, 0, stream>>>(buf1, W4, b4, buf0);
  // Layer 5: S_IN=2, G=32 (1024 groups), 128 images/block
  k_layer<2, 32, 128, 1><<<dim3(1024, 2, 1), 256, 0, stream>>>(buf0, W5, b5, buf1);
  // FT
  k_ft<<<4096, 256, 0, stream>>>(buf1, Wft, bft, (float*)d_out);
}

// Round 3
// 1080.890 us; speedup vs baseline: 2.3873x; 2.3873x over previous
//
#include <hip/hip_runtime.h>
#include <hip/hip_bf16.h>

// ButterFlyNet2D forward, fp32, register-row-blocked.
// Layer k output layout: [B=256][CH_k][S_k][S_k], CH_k = 4^(k+1)*16, S_k = 2^(5-k).
// Intermediates: 16,777,216 floats (64 MiB) each, ping-pong in d_ws (needs 128 MiB).

// Load CC conv-columns (+1 wrap col) of one staged row into registers (broadcast LDS reads).
template <int CC, int S_IN, int NCHUNK>
__device__ __forceinline__ void load_row(const float* __restrict__ row, int c0, float* r) {
  if constexpr (CC >= 4) {
#pragma unroll
    for (int j = 0; j < CC / 4; ++j) {
      float4 v = *(const float4*)(row + c0 + 4 * j);
      r[4 * j] = v.x; r[4 * j + 1] = v.y; r[4 * j + 2] = v.z; r[4 * j + 3] = v.w;
    }
  } else {  // CC == 2
    float2 v = *(const float2*)(row + c0);
    r[0] = v.x; r[1] = v.y;
  }
  if constexpr (NCHUNK == 1) r[CC] = r[0];                 // wrap col == col 0 == r[0]
  else r[CC] = row[(c0 + CC) & (S_IN - 1)];                // chunked: load wrap/next col
}

// ---------------- Layer 0: split -> conv(4->64,2x2) -> relu -> wrap-pad -> pool ----------------
// Block = (image b, ph-quarter). Lane = oc. Row accumulators, relu split p=max(v,0), m=p-v.
__global__ __launch_bounds__(256) void k_layer0(
    const float* __restrict__ x, const float* __restrict__ W0,
    const float* __restrict__ b0, float* __restrict__ out) {
  __shared__ __align__(16) float xs[17 * 64];
  const int b = blockIdx.x, p0 = blockIdx.y * 8;
  const float* xb = x + (size_t)b * 4096;
  for (int i = threadIdx.x; i < 17 * 16; i += 256) {
    int lr = i >> 4, c4 = i & 15;
    ((float4*)xs)[i] = *(const float4*)(xb + ((2 * p0 + lr) & 63) * 64 + c4 * 4);
  }
  __syncthreads();
  const int oc = threadIdx.x & 63, wv = threadIdx.x >> 6;
  float wp[2][2], wm[2][2];
#pragma unroll
  for (int kh = 0; kh < 2; ++kh)
#pragma unroll
    for (int kw = 0; kw < 2; ++kw) {
      wp[kh][kw] = W0[((oc * 4 + 0) * 2 + kh) * 2 + kw];
      wm[kh][kw] = W0[((oc * 4 + 1) * 2 + kh) * 2 + kw];
    }
  const float bias = b0[oc];
  float* ob = out + (size_t)b * 65536 + (size_t)oc * 1024;
  for (int t = wv; t < 64; t += 4) {       // 8 ph rows x 8 col-chunks of 8
    const int phl = t >> 3, c0 = (t & 7) * 8;
    const int lrA = 2 * phl;
    float vA[9], vB[9], vC[9];
    load_row<8, 64, 8>(xs + lrA * 64, c0, vA);
    load_row<8, 64, 8>(xs + (lrA + 1) * 64, c0, vB);
    load_row<8, 64, 8>(xs + (lrA + 2) * 64, c0, vC);
    float pA[9], mA[9], pB[9], mB[9], pC[9], mC[9];
#pragma unroll
    for (int j = 0; j < 9; ++j) {
      pA[j] = fmaxf(vA[j], 0.f); mA[j] = pA[j] - vA[j];
      pB[j] = fmaxf(vB[j], 0.f); mB[j] = pB[j] - vB[j];
      pC[j] = fmaxf(vC[j], 0.f); mC[j] = pC[j] - vC[j];
    }
    float sc0[8], sc1[8];
#pragma unroll
    for (int q = 0; q < 8; ++q) {
      sc0[q] = bias + wp[0][0] * pA[q] + wm[0][0] * mA[q] + wp[0][1] * pA[q + 1] + wm[0][1] * mA[q + 1]
                    + wp[1][0] * pB[q] + wm[1][0] * mB[q] + wp[1][1] * pB[q + 1] + wm[1][1] * mB[q + 1];
      sc1[q] = bias + wp[0][0] * pB[q] + wm[0][0] * mB[q] + wp[0][1] * pB[q + 1] + wm[0][1] * mB[q + 1]
                    + wp[1][0] * pC[q] + wm[1][0] * mC[q] + wp[1][1] * pC[q + 1] + wm[1][1] * mC[q + 1];
    }
    float po[4];
#pragma unroll
    for (int p = 0; p < 4; ++p)
      po[p] = 0.25f * (fmaxf(sc0[2 * p], 0.f) + fmaxf(sc0[2 * p + 1], 0.f) +
                       fmaxf(sc1[2 * p], 0.f) + fmaxf(sc1[2 * p + 1], 0.f));
    *(float4*)(ob + (p0 + phl) * 32 + c0 / 2) = make_float4(po[0], po[1], po[2], po[3]);
  }
}

// ---------------- Recursion layers 1..5 ----------------
// Grouped conv 16->64 (2x2, circular pad) + bias + relu + pool + butterfly permute.
// Lane = oc (64). Per task a wave computes a full conv row-pair for CC columns:
// 32 independent accumulators, 3 row loads per ic reused across all columns.
template <int S_IN, int G, int BPB, int PSPLIT, int CC>
__global__ __launch_bounds__(256) void k_layer(
    const float* __restrict__ yin, const float* __restrict__ W,
    const float* __restrict__ Bv, float* __restrict__ yout) {
  constexpr int NB = G * G;
  constexpr int S_OUT = S_IN / 2;
  constexpr int PH_B = S_OUT / PSPLIT;
  constexpr int NCHUNK = S_IN / CC;
  constexpr int ROWS = (PSPLIT == 1) ? S_IN : (2 * PH_B + 1);
  constexpr int INPG = 16 * ROWS * S_IN;
  constexpr int INPG_FULL = 16 * S_IN * S_IN;
  __shared__ __align__(16) float wsm[64 * 68];   // [oc][ic*4+k], stride 68 (16B-aligned rows)
  __shared__ __align__(16) float ins[BPB * INPG];
  const int gi = blockIdx.x, bc = blockIdx.y;
  const int p0 = (PSPLIT == 1) ? 0 : blockIdx.z * PH_B;
  const int tid = threadIdx.x;
  const float* wsrc = W + (size_t)gi * 4096;
  for (int i = tid; i < 4096; i += 256) wsm[(i >> 6) * 68 + (i & 63)] = wsrc[i];
  constexpr int N4 = BPB * INPG / 4;
  if constexpr (PSPLIT == 1) {
    for (int i = tid; i < N4; i += 256) {
      int bi = i / (INPG / 4), rem = i - bi * (INPG / 4);
      ((float4*)ins)[i] =
          *(const float4*)(yin + ((size_t)(bc * BPB + bi) * NB + gi) * INPG_FULL + rem * 4);
    }
  } else {
    constexpr int RQ = S_IN / 4;
    for (int i = tid; i < N4; i += 256) {
      int bi = i / (INPG / 4), rem = i - bi * (INPG / 4);
      int ic = rem / (ROWS * RQ); int rem2 = rem - ic * (ROWS * RQ);
      int lr = rem2 / RQ, c4 = rem2 - lr * RQ;
      int gr = (2 * p0 + lr) & (S_IN - 1);
      ((float4*)ins)[i] = *(const float4*)(yin + ((size_t)(bc * BPB + bi) * NB + gi) * INPG_FULL +
                                           (ic * S_IN + gr) * S_IN + c4 * 4);
    }
  }
  __syncthreads();
  const int oc = tid & 63, wv = tid >> 6;
  const float breg = Bv[(size_t)gi * 64 + oc];
  const int A_y = gi / G, A_x = gi - A_y * G;
  const int och = (((A_y * 2 + (oc >> 5)) * G + A_x) * 2 + ((oc >> 4) & 1)) * 16 + (oc & 15);
  constexpr int NTASK = BPB * PH_B * NCHUNK;
  for (int t = wv; t < NTASK; t += 4) {
    const int bi = t / (PH_B * NCHUNK);
    int rest = t - bi * (PH_B * NCHUNK);
    const int phl = rest / NCHUNK;
    const int c0 = (rest - phl * NCHUNK) * CC;
    const int lrA = 2 * phl;
    const int lrC = (PSPLIT == 1) ? ((2 * phl + 2) & (S_IN - 1)) : (2 * phl + 2);
    float sc0[CC], sc1[CC];
#pragma unroll
    for (int q = 0; q < CC; ++q) { sc0[q] = breg; sc1[q] = breg; }
    const float* inb = ins + bi * INPG;
#pragma unroll 2
    for (int ic = 0; ic < 16; ++ic) {
      const float* base = inb + ic * (ROWS * S_IN);
      float rA[CC + 1], rB[CC + 1], rC[CC + 1];
      load_row<CC, S_IN, NCHUNK>(base + lrA * S_IN, c0, rA);
      load_row<CC, S_IN, NCHUNK>(base + (lrA + 1) * S_IN, c0, rB);
      load_row<CC, S_IN, NCHUNK>(base + lrC * S_IN, c0, rC);
      float4 w = *(const float4*)&wsm[oc * 68 + ic * 4];
#pragma unroll
      for (int q = 0; q < CC; ++q) {
        sc0[q] += w.x * rA[q] + w.y * rA[q + 1] + w.z * rB[q] + w.w * rB[q + 1];
        sc1[q] += w.x * rB[q] + w.y * rB[q + 1] + w.z * rC[q] + w.w * rC[q + 1];
      }
    }
    float po[CC / 2];
#pragma unroll
    for (int p = 0; p < CC / 2; ++p)
      po[p] = 0.25f * (fmaxf(sc0[2 * p], 0.f) + fmaxf(sc0[2 * p + 1], 0.f) +
                       fmaxf(sc1[2 * p], 0.f) + fmaxf(sc1[2 * p + 1], 0.f));
    const int b = bc * BPB + bi;
    const int ph = p0 + phl;
    float* op = yout + ((size_t)b * (NB * 64) + och) * (S_OUT * S_OUT) + ph * S_OUT + c0 / 2;
    if constexpr (CC / 2 >= 4) {
#pragma unroll
      for (int j = 0; j < CC / 8; ++j)
        *(float4*)(op + 4 * j) = make_float4(po[4 * j], po[4 * j + 1], po[4 * j + 2], po[4 * j + 3]);
    } else if constexpr (CC / 2 == 2) {
      *(float2*)op = make_float2(po[0], po[1]);
    } else {
      *op = po[0];
    }
  }
}

// ---------------- FT layer: per-block 16->4 contraction + real/imag ----------------
__global__ __launch_bounds__(256) void k_ft(
    const float* __restrict__ v, const float* __restrict__ Wft,
    const float* __restrict__ bft, float* __restrict__ out) {
  const int idx = blockIdx.x * 256 + threadIdx.x;
  const int b = idx >> 12;
  const int n = idx & 4095;
  const float4* vp = (const float4*)(v + ((size_t)b * 4096 + n) * 16);
  float4 v0 = vp[0], v1 = vp[1], v2 = vp[2], v3 = vp[3];
  const float4* wp = (const float4*)(Wft + (size_t)n * 64);
  float f[4];
#pragma unroll
  for (int o = 0; o < 4; o++) {
    float4 w0 = wp[o * 4 + 0], w1 = wp[o * 4 + 1], w2 = wp[o * 4 + 2], w3 = wp[o * 4 + 3];
    f[o] = bft[n * 4 + o]
         + v0.x * w0.x + v0.y * w0.y + v0.z * w0.z + v0.w * w0.w
         + v1.x * w1.x + v1.y * w1.y + v1.z * w1.z + v1.w * w1.w
         + v2.x * w2.x + v2.y * w2.y + v2.z * w2.z + v2.w * w2.w
         + v3.x * w3.x + v3.y * w3.y + v3.z * w3.z + v3.w * w3.w;
  }
  out[(size_t)b * 8192 + n] = f[0] - f[1];
  out[(size_t)b * 8192 + 4096 + n] = f[2] - f[3];
}

extern "C" void kernel_launch(void* const* d_in, const int* in_sizes, int n_in,
                              void* d_out, int out_size, void* d_ws, size_t ws_size,
                              hipStream_t stream) {
  const float* x   = (const float*)d_in[0];
  const float* W0  = (const float*)d_in[1];
  const float* b0  = (const float*)d_in[2];
  const float* Wft = (const float*)d_in[3];
  const float* bft = (const float*)d_in[4];
  const float* W1 = (const float*)d_in[5];  const float* b1 = (const float*)d_in[6];
  const float* W2 = (const float*)d_in[7];  const float* b2 = (const float*)d_in[8];
  const float* W3 = (const float*)d_in[9];  const float* b3 = (const float*)d_in[10];
  const float* W4 = (const float*)d_in[11]; const float* b4 = (const float*)d_in[12];
  const float* W5 = (const float*)d_in[13]; const float* b5 = (const float*)d_in[14];

  float* buf0 = (float*)d_ws;
  float* buf1 = buf0 + (size_t)16777216;

  k_layer0<<<dim3(256, 4), 256, 0, stream>>>(x, W0, b0, buf0);
  // Layer 1: S_IN=32, G=2, 1 img/block, ph split 2, col chunks of 16
  k_layer<32, 2, 1, 2, 16><<<dim3(4, 256, 2), 256, 0, stream>>>(buf0, W1, b1, buf1);
  // Layer 2: S_IN=16, G=4, 2 img/block
  k_layer<16, 4, 2, 1, 16><<<dim3(16, 128, 1), 256, 0, stream>>>(buf1, W2, b2, buf0);
  // Layer 3: S_IN=8, G=8, 8 img/block
  k_layer<8, 8, 8, 1, 8><<<dim3(64, 32, 1), 256, 0, stream>>>(buf0, W3, b3, buf1);
  // Layer 4: S_IN=4, G=16, 32 img/block
  k_layer<4, 16, 32, 1, 4><<<dim3(256, 8, 1), 256, 0, stream>>>(buf1, W4, b4, buf0);
  // Layer 5: S_IN=2, G=32, 128 img/block
  k_layer<2, 32, 128, 1, 2><<<dim3(1024, 2, 1), 256, 0, stream>>>(buf0, W5, b5, buf1);
  // FT
  k_ft<<<4096, 256, 0, stream>>>(buf1, Wft, bft, (float*)d_out);
}

// Round 5
// 286.786 us; speedup vs baseline: 8.9975x; 3.7690x over previous
//
#include <hip/hip_runtime.h>
#include <hip/hip_bf16.h>

// ButterFlyNet2D forward — MFMA bf16 path.
// Intermediate layout after every layer: [B][group][y][x][16 ic] bf16, where
// "group" is the NEXT layer's group index (butterfly permute folded into store).
// Buffers: 16.7M bf16 = 33.5 MB each, ping-pong in d_ws.

typedef __attribute__((ext_vector_type(4))) float f32x4;
typedef __attribute__((ext_vector_type(8))) short s16x8;

__device__ __forceinline__ short f2bf(float f) {
  union { float f; unsigned u; } v; v.f = f;
  unsigned r = v.u + 0x7fff + ((v.u >> 16) & 1);   // RNE
  return (short)(r >> 16);
}
__device__ __forceinline__ float bf2f(short s) {
  union { unsigned u; float f; } v; v.u = ((unsigned)(unsigned short)s) << 16;
  return v.f;
}

// ---------------- Layer 0: split -> conv(4->64,2x2) -> relu -> wrap-pad -> pool ----------------
// Output: [b][g=oc>>4][y 0..31][x 0..31][c=oc&15] bf16.
__global__ __launch_bounds__(256) void k_layer0(
    const float* __restrict__ x, const float* __restrict__ W0,
    const float* __restrict__ b0, short* __restrict__ out) {
  __shared__ __align__(16) float xs[17 * 64];
  const int b = blockIdx.x, p0 = blockIdx.y * 8;
  const float* xb = x + (size_t)b * 4096;
  for (int i = threadIdx.x; i < 17 * 16; i += 256) {
    int lr = i >> 4, c4 = i & 15;
    ((float4*)xs)[i] = *(const float4*)(xb + ((2 * p0 + lr) & 63) * 64 + c4 * 4);
  }
  __syncthreads();
  const int oc = threadIdx.x & 63, wv = threadIdx.x >> 6;
  float wp[2][2], wm[2][2];
#pragma unroll
  for (int kh = 0; kh < 2; ++kh)
#pragma unroll
    for (int kw = 0; kw < 2; ++kw) {
      wp[kh][kw] = W0[((oc * 4 + 0) * 2 + kh) * 2 + kw];
      wm[kh][kw] = W0[((oc * 4 + 1) * 2 + kh) * 2 + kw];
    }
  const float bias = b0[oc];
  short* ob = out + ((size_t)b * 4 + (oc >> 4)) * 16384 + (oc & 15);
  for (int t = wv; t < 64; t += 4) {   // 8 ph rows x 8 col-chunks (8 conv cols -> 4 pooled)
    const int phl = t >> 3, c0 = (t & 7) * 8;
    const int lrA = 2 * phl;
    float vA[9], vB[9], vC[9];
#pragma unroll
    for (int j = 0; j < 8; ++j) {
      vA[j] = xs[lrA * 64 + c0 + j];
      vB[j] = xs[(lrA + 1) * 64 + c0 + j];
      vC[j] = xs[(lrA + 2) * 64 + c0 + j];
    }
    vA[8] = xs[lrA * 64 + ((c0 + 8) & 63)];
    vB[8] = xs[(lrA + 1) * 64 + ((c0 + 8) & 63)];
    vC[8] = xs[(lrA + 2) * 64 + ((c0 + 8) & 63)];
    float pA[9], mA[9], pB[9], mB[9], pC[9], mC[9];
#pragma unroll
    for (int j = 0; j < 9; ++j) {
      pA[j] = fmaxf(vA[j], 0.f); mA[j] = pA[j] - vA[j];
      pB[j] = fmaxf(vB[j], 0.f); mB[j] = pB[j] - vB[j];
      pC[j] = fmaxf(vC[j], 0.f); mC[j] = pC[j] - vC[j];
    }
    float sc0[8], sc1[8];
#pragma unroll
    for (int q = 0; q < 8; ++q) {
      sc0[q] = bias + wp[0][0] * pA[q] + wm[0][0] * mA[q] + wp[0][1] * pA[q + 1] + wm[0][1] * mA[q + 1]
                    + wp[1][0] * pB[q] + wm[1][0] * mB[q] + wp[1][1] * pB[q + 1] + wm[1][1] * mB[q + 1];
      sc1[q] = bias + wp[0][0] * pB[q] + wm[0][0] * mB[q] + wp[0][1] * pB[q + 1] + wm[0][1] * mB[q + 1]
                    + wp[1][0] * pC[q] + wm[1][0] * mC[q] + wp[1][1] * pC[q + 1] + wm[1][1] * mC[q + 1];
    }
#pragma unroll
    for (int p = 0; p < 4; ++p) {
      float po = 0.25f * (fmaxf(sc0[2 * p], 0.f) + fmaxf(sc0[2 * p + 1], 0.f) +
                          fmaxf(sc1[2 * p], 0.f) + fmaxf(sc1[2 * p + 1], 0.f));
      ob[((p0 + phl) * 32 + c0 / 2 + p) * 16] = f2bf(po);
    }
  }
}

// ---------------- MFMA recursion layer ----------------
// Grouped conv 16->64 (2x2 circular) + bias + relu + pool + butterfly store.
// Block = (group gi, image-chunk of IMB). 4 waves; per wave-iter: 16 pooled
// positions x 64 oc, 4 pool-phase accumulators, 8 B-frag ds_read_b128, 32 mfma.
template <int S, int G, int IMB>
__global__ __launch_bounds__(256) void k_bconv(
    const short* __restrict__ yin, const float* __restrict__ W,
    const float* __restrict__ Bv, short* __restrict__ yout) {
  constexpr int NB = G * G;
  constexpr int SO = S / 2;
  constexpr int LOG_SO = (SO == 16) ? 4 : (SO == 8) ? 3 : (SO == 4) ? 2 : (SO == 2) ? 1 : 0;
  constexpr int SP = S + 1;              // staged rows/cols incl. wrap (odd -> bank spread)
  constexpr int IMG_PIX = SP * SP;
  constexpr int ITERS = IMB * SO * SO / 64;
  __shared__ __align__(16) short ins[IMB * IMG_PIX * 16];
  __shared__ __align__(16) short wl[4096];
  const int gi = blockIdx.x;
  const int b0 = blockIdx.y * IMB;
  const int tid = threadIdx.x;

  // stage weights into A-fragment order: idx = (((t*2+dy)*4+g)*16+row)*8+j, k=8g+j=(dx*16+ic)
  const float* wsrc = W + (size_t)gi * 4096;
  for (int i = tid; i < 4096; i += 256) {
    int j = i & 7, row = (i >> 3) & 15, g = (i >> 7) & 3, dy = (i >> 9) & 1, t = i >> 10;
    int k = 8 * g + j;
    int ic = k & 15, dx = k >> 4;
    wl[i] = f2bf(wsrc[((t * 16 + row) * 16 + ic) * 4 + dy * 2 + dx]);
  }
  // stage input, channel-last, wrap row/col duplicated
  constexpr int GRAN = IMB * IMG_PIX * 2;   // 16B granules (8 ic each)
  for (int i = tid; i < GRAN; i += 256) {
    int half = i & 1, q = i >> 1;
    int xx = q % SP; int t2 = q / SP; int yy = t2 % SP; int bi = t2 / SP;
    size_t src = (((size_t)(b0 + bi) * NB + gi) * (S * S) + (yy & (S - 1)) * S + (xx & (S - 1))) * 16 + half * 8;
    *(float4*)&ins[(size_t)q * 16 + half * 8] = *(const float4*)&yin[src];
  }
  __syncthreads();

  const int lane = tid & 63, wv = tid >> 6;
  const int lp = lane & 15, g4 = lane >> 4;
  const int dxg = g4 >> 1, ich = g4 & 1;

  // A-frags: whole 64x64 weight matrix lives in 32 VGPR/lane
  s16x8 af[4][2];
#pragma unroll
  for (int t = 0; t < 4; ++t)
#pragma unroll
    for (int dy = 0; dy < 2; ++dy)
      af[t][dy] = *(const s16x8*)&wl[(((t * 2 + dy) * 4 + g4) * 16 + lp) * 8];
  // bias (as accumulator init); lane's 4 C-rows = oc t*16 + g4*4 .. +3
  f32x4 bv[4];
#pragma unroll
  for (int t = 0; t < 4; ++t)
    bv[t] = *(const f32x4*)&Bv[(size_t)gi * 64 + t * 16 + g4 * 4];

  const int A_y = gi / G, A_x = gi - A_y * G;

  for (int it = 0; it < ITERS; ++it) {
    const int pg = it * 64 + wv * 16 + lp;
    const int px = pg & (SO - 1);
    const int py = (pg >> LOG_SO) & (SO - 1);
    const int bi = pg >> (2 * LOG_SO);
    const short* pb = ins + ((size_t)bi * IMG_PIX + (2 * py) * SP + 2 * px + dxg) * 16 + ich * 8;
    const short* r0 = pb;
    const short* r1 = pb + SP * 16;
    const short* r2 = pb + 2 * SP * 16;
    f32x4 acc[4][4];
#pragma unroll
    for (int t = 0; t < 4; ++t)
#pragma unroll
      for (int ph = 0; ph < 4; ++ph) acc[t][ph] = bv[t];
#pragma unroll
    for (int phy = 0; phy < 2; ++phy)
#pragma unroll
      for (int phx = 0; phx < 2; ++phx) {
        const int ph = phy * 2 + phx;
#pragma unroll
        for (int dy = 0; dy < 2; ++dy) {
          const short* rp = (phy + dy == 0) ? r0 : (phy + dy == 1) ? r1 : r2;
          s16x8 bf = *(const s16x8*)(rp + phx * 16);
#pragma unroll
          for (int t = 0; t < 4; ++t)
            acc[t][ph] = __builtin_amdgcn_mfma_f32_16x16x32_bf16(af[t][dy], bf, acc[t][ph], 0, 0, 0);
        }
      }
    // epilogue: relu each conv position, avg-pool, bf16, butterfly store
    const int b = b0 + bi;
#pragma unroll
    for (int t = 0; t < 4; ++t) {
      short pk[4];
#pragma unroll
      for (int r = 0; r < 4; ++r) {
        float po = 0.25f * (fmaxf(acc[t][0][r], 0.f) + fmaxf(acc[t][1][r], 0.f) +
                            fmaxf(acc[t][2][r], 0.f) + fmaxf(acc[t][3][r], 0.f));
        pk[r] = f2bf(po);
      }
      const int gip = (A_y * 2 + (t >> 1)) * (2 * G) + A_x * 2 + (t & 1);
      size_t dst = (((size_t)b * (4 * NB) + gip) * (SO * SO) + py * SO + px) * 16 + g4 * 4;
      *(short4*)&yout[dst] = make_short4(pk[0], pk[1], pk[2], pk[3]);
    }
  }
}

// ---------------- FT layer: per-block 16->4 contraction + real/imag ----------------
__global__ __launch_bounds__(256) void k_ft(
    const short* __restrict__ v, const float* __restrict__ Wft,
    const float* __restrict__ bft, float* __restrict__ out) {
  const int idx = blockIdx.x * 256 + threadIdx.x;
  const int b = idx >> 12;
  const int n = idx & 4095;
  const short* vp = v + ((size_t)b * 4096 + n) * 16;
  s16x8 a0 = *(const s16x8*)vp;
  s16x8 a1 = *(const s16x8*)(vp + 8);
  float vv[16];
#pragma unroll
  for (int j = 0; j < 8; ++j) { vv[j] = bf2f(a0[j]); vv[8 + j] = bf2f(a1[j]); }
  const float* wp = Wft + (size_t)n * 64;
  float f[4];
#pragma unroll
  for (int o = 0; o < 4; o++) {
    float s = bft[n * 4 + o];
#pragma unroll
    for (int j = 0; j < 16; ++j) s += vv[j] * wp[o * 16 + j];
    f[o] = s;
  }
  out[(size_t)b * 8192 + n] = f[0] - f[1];
  out[(size_t)b * 8192 + 4096 + n] = f[2] - f[3];
}

extern "C" void kernel_launch(void* const* d_in, const int* in_sizes, int n_in,
                              void* d_out, int out_size, void* d_ws, size_t ws_size,
                              hipStream_t stream) {
  const float* x   = (const float*)d_in[0];
  const float* W0  = (const float*)d_in[1];
  const float* b0  = (const float*)d_in[2];
  const float* Wft = (const float*)d_in[3];
  const float* bft = (const float*)d_in[4];
  const float* W1 = (const float*)d_in[5];  const float* b1 = (const float*)d_in[6];
  const float* W2 = (const float*)d_in[7];  const float* b2 = (const float*)d_in[8];
  const float* W3 = (const float*)d_in[9];  const float* b3 = (const float*)d_in[10];
  const float* W4 = (const float*)d_in[11]; const float* b4 = (const float*)d_in[12];
  const float* W5 = (const float*)d_in[13]; const float* b5 = (const float*)d_in[14];

  short* buf0 = (short*)d_ws;                       // 16.7M bf16 = 33.5 MB
  short* buf1 = buf0 + (size_t)16777216;

  k_layer0<<<dim3(256, 4), 256, 0, stream>>>(x, W0, b0, buf0);
  // L1: S=32, G=2, 1 img/block   -> grid (4 groups, 256)
  k_bconv<32, 2, 1><<<dim3(4, 256), 256, 0, stream>>>(buf0, W1, b1, buf1);
  // L2: S=16, G=4, 4 img/block   -> grid (16, 64)
  k_bconv<16, 4, 4><<<dim3(16, 64), 256, 0, stream>>>(buf1, W2, b2, buf0);
  // L3: S=8, G=8, 16 img/block   -> grid (64, 16)
  k_bconv<8, 8, 16><<<dim3(64, 16), 256, 0, stream>>>(buf0, W3, b3, buf1);
  // L4: S=4, G=16, 32 img/block  -> grid (256, 8)
  k_bconv<4, 16, 32><<<dim3(256, 8), 256, 0, stream>>>(buf1, W4, b4, buf0);
  // L5: S=2, G=32, 128 img/block -> grid (1024, 2)
  k_bconv<2, 32, 128><<<dim3(1024, 2), 256, 0, stream>>>(buf0, W5, b5, buf1);
  // FT (bf16 v -> fp32 out)
  k_ft<<<4096, 256, 0, stream>>>(buf1, Wft, bft, (float*)d_out);
}

// Round 6
// 269.528 us; speedup vs baseline: 9.5736x; 1.0640x over previous
//
#include <hip/hip_runtime.h>
#include <hip/hip_bf16.h>

// ButterFlyNet2D forward — MFMA bf16 path, round 6.
// Intermediate layout after every layer: [B][group][y][x][16 ic] bf16, where
// "group" is the NEXT layer's group index (butterfly permute folded into store).
// Buffers: 16.7M bf16 = 33.5 MB each, ping-pong in d_ws.

typedef __attribute__((ext_vector_type(4))) float f32x4;
typedef __attribute__((ext_vector_type(8))) short s16x8;

__device__ __forceinline__ short f2bf(float f) {
  union { float f; unsigned u; } v; v.f = f;
  unsigned r = v.u + 0x7fff + ((v.u >> 16) & 1);   // RNE
  return (short)(r >> 16);
}
__device__ __forceinline__ float bf2f(short s) {
  union { unsigned u; float f; } v; v.u = ((unsigned)(unsigned short)s) << 16;
  return v.f;
}
constexpr int ilog2c(int v) { return v <= 1 ? 0 : 1 + ilog2c(v / 2); }

// ---------------- Layer 0: split -> conv(4->64,2x2) -> relu -> wrap-pad -> pool ----------------
// Output: [b][g=oc>>4][y 0..31][x 0..31][c=oc&15] bf16. LDS-staged coalesced stores.
__global__ __launch_bounds__(256) void k_layer0(
    const float* __restrict__ x, const float* __restrict__ W0,
    const float* __restrict__ b0, short* __restrict__ out) {
  constexpr int GS = 4112;                 // g-region stride (shorts): 8-word bank shift per g
  __shared__ __align__(16) float xs[17 * 64];
  __shared__ __align__(16) short os[4 * GS];
  const int b = blockIdx.x, p0 = blockIdx.y * 8;
  const float* xb = x + (size_t)b * 4096;
  for (int i = threadIdx.x; i < 17 * 16; i += 256) {
    int lr = i >> 4, c4 = i & 15;
    ((float4*)xs)[i] = *(const float4*)(xb + ((2 * p0 + lr) & 63) * 64 + c4 * 4);
  }
  __syncthreads();
  const int oc = threadIdx.x & 63, wv = threadIdx.x >> 6;
  const int g = oc >> 4, c = oc & 15;
  float wp[2][2], wm[2][2];
#pragma unroll
  for (int kh = 0; kh < 2; ++kh)
#pragma unroll
    for (int kw = 0; kw < 2; ++kw) {
      wp[kh][kw] = W0[((oc * 4 + 0) * 2 + kh) * 2 + kw];
      wm[kh][kw] = W0[((oc * 4 + 1) * 2 + kh) * 2 + kw];
    }
  const float bias = b0[oc];
  for (int t = wv; t < 64; t += 4) {   // 8 local ph rows x 8 col-chunks (8 conv cols -> 4 pooled)
    const int phl = t >> 3, c0 = (t & 7) * 8;
    const int lrA = 2 * phl;
    float vA[9], vB[9], vC[9];
#pragma unroll
    for (int j = 0; j < 8; ++j) {
      vA[j] = xs[lrA * 64 + c0 + j];
      vB[j] = xs[(lrA + 1) * 64 + c0 + j];
      vC[j] = xs[(lrA + 2) * 64 + c0 + j];
    }
    vA[8] = xs[lrA * 64 + ((c0 + 8) & 63)];
    vB[8] = xs[(lrA + 1) * 64 + ((c0 + 8) & 63)];
    vC[8] = xs[(lrA + 2) * 64 + ((c0 + 8) & 63)];
    float pA[9], mA[9], pB[9], mB[9], pC[9], mC[9];
#pragma unroll
    for (int j = 0; j < 9; ++j) {
      pA[j] = fmaxf(vA[j], 0.f); mA[j] = pA[j] - vA[j];
      pB[j] = fmaxf(vB[j], 0.f); mB[j] = pB[j] - vB[j];
      pC[j] = fmaxf(vC[j], 0.f); mC[j] = pC[j] - vC[j];
    }
    float sc0[8], sc1[8];
#pragma unroll
    for (int q = 0; q < 8; ++q) {
      sc0[q] = bias + wp[0][0] * pA[q] + wm[0][0] * mA[q] + wp[0][1] * pA[q + 1] + wm[0][1] * mA[q + 1]
                    + wp[1][0] * pB[q] + wm[1][0] * mB[q] + wp[1][1] * pB[q + 1] + wm[1][1] * mB[q + 1];
      sc1[q] = bias + wp[0][0] * pB[q] + wm[0][0] * mB[q] + wp[0][1] * pB[q + 1] + wm[0][1] * mB[q + 1]
                    + wp[1][0] * pC[q] + wm[1][0] * mC[q] + wp[1][1] * pC[q + 1] + wm[1][1] * mC[q + 1];
    }
#pragma unroll
    for (int p = 0; p < 4; ++p) {
      float po = 0.25f * (fmaxf(sc0[2 * p], 0.f) + fmaxf(sc0[2 * p + 1], 0.f) +
                          fmaxf(sc1[2 * p], 0.f) + fmaxf(sc1[2 * p + 1], 0.f));
      os[g * GS + (phl * 32 + c0 / 2 + p) * 16 + c] = f2bf(po);
    }
  }
  __syncthreads();
#pragma unroll
  for (int gg = 0; gg < 4; ++gg) {
    short* dst = out + ((size_t)b * 4 + gg) * 16384 + (size_t)p0 * 512;
    for (int i = threadIdx.x; i < 512; i += 256)
      *(float4*)&dst[i * 8] = *(const float4*)&os[gg * GS + i * 8];
  }
}

// ---------------- MFMA recursion layer ----------------
// Grouped conv 16->64 (2x2 circular) + bias + relu + pool + butterfly store.
// Block = (image-chunk bc, group gi, ph-chunk z). 4 waves; per wave-iter: 16 pooled
// positions x 64 oc, 4 pool-phase accumulators, 8 B-frag ds_read_b128, 32 mfma.
template <int S, int G, int IMB, int PH>
__global__ __launch_bounds__(256) void k_bconv(
    const short* __restrict__ yin, const float* __restrict__ W,
    const float* __restrict__ Bv, short* __restrict__ yout) {
  constexpr int NB = G * G;
  constexpr int SO = S / 2;
  constexpr int LOG_SO = ilog2c(SO);
  constexpr int LOG_PH = ilog2c(PH);
  constexpr int SP = S + 1;              // staged cols incl. wrap (odd -> bank spread)
  constexpr int ROWS = 2 * PH + 1;       // staged rows incl. wrap
  constexpr int IMG_PIX = ROWS * SP;
  constexpr int ITERS = IMB * PH * SO / 64;
  __shared__ __align__(16) short ins[IMB * IMG_PIX * 16];
  __shared__ __align__(16) short wl[4096];
  const int gi = blockIdx.y;
  const int b0 = blockIdx.x * IMB;
  const int p0 = blockIdx.z * PH;
  const int tid = threadIdx.x;

  // stage weights into A-fragment order: idx = (((t*2+dy)*4+g)*16+row)*8+j, k=8g+j=(dx*16+ic)
  const float* wsrc = W + (size_t)gi * 4096;
  for (int i = tid; i < 4096; i += 256) {
    int j = i & 7, row = (i >> 3) & 15, g = (i >> 7) & 3, dy = (i >> 9) & 1, t = i >> 10;
    int k = 8 * g + j;
    int ic = k & 15, dx = k >> 4;
    wl[i] = f2bf(wsrc[((t * 16 + row) * 16 + ic) * 4 + dy * 2 + dx]);
  }
  // stage input, channel-last, wrap row/col duplicated
  constexpr int GRAN = IMB * IMG_PIX * 2;   // 16B granules (8 ic each)
  for (int i = tid; i < GRAN; i += 256) {
    int half = i & 1, q = i >> 1;
    int xx = q % SP; int t2 = q / SP; int lr = t2 % ROWS; int bi2 = t2 / ROWS;
    int gr = (2 * p0 + lr) & (S - 1);
    int gx = xx & (S - 1);
    size_t src = (((size_t)(b0 + bi2) * NB + gi) * (S * S) + gr * S + gx) * 16 + half * 8;
    *(float4*)&ins[(size_t)q * 16 + half * 8] = *(const float4*)&yin[src];
  }
  __syncthreads();

  const int lane = tid & 63, wv = tid >> 6;
  const int lp = lane & 15, g4 = lane >> 4;
  const int dxg = g4 >> 1, ich = g4 & 1;

  // A-frags: whole 64x64 weight matrix lives in 32 VGPR/lane
  s16x8 af[4][2];
#pragma unroll
  for (int t = 0; t < 4; ++t)
#pragma unroll
    for (int dy = 0; dy < 2; ++dy)
      af[t][dy] = *(const s16x8*)&wl[(((t * 2 + dy) * 4 + g4) * 16 + lp) * 8];
  // bias (as accumulator init); lane's 4 C-rows = oc t*16 + g4*4 .. +3
  f32x4 bv[4];
#pragma unroll
  for (int t = 0; t < 4; ++t)
    bv[t] = *(const f32x4*)&Bv[(size_t)gi * 64 + t * 16 + g4 * 4];

  const int A_y = gi / G, A_x = gi - A_y * G;

#pragma unroll
  for (int it = 0; it < ITERS; ++it) {
    const int pg = it * 64 + wv * 16 + lp;
    const int px = pg & (SO - 1);
    const int pyl = (pg >> LOG_SO) & (PH - 1);
    const int bi = pg >> (LOG_SO + LOG_PH);
    const int py = p0 + pyl;
    const short* pb = ins + ((size_t)(bi * ROWS + 2 * pyl) * SP + 2 * px + dxg) * 16 + ich * 8;
    const short* r0 = pb;
    const short* r1 = pb + SP * 16;
    const short* r2 = pb + 2 * SP * 16;
    f32x4 acc[4][4];
#pragma unroll
    for (int t = 0; t < 4; ++t)
#pragma unroll
      for (int ph = 0; ph < 4; ++ph) acc[t][ph] = bv[t];
#pragma unroll
    for (int phy = 0; phy < 2; ++phy)
#pragma unroll
      for (int phx = 0; phx < 2; ++phx) {
        const int ph = phy * 2 + phx;
#pragma unroll
        for (int dy = 0; dy < 2; ++dy) {
          const short* rp = (phy + dy == 0) ? r0 : (phy + dy == 1) ? r1 : r2;
          s16x8 bf = *(const s16x8*)(rp + phx * 16);
#pragma unroll
          for (int t = 0; t < 4; ++t)
            acc[t][ph] = __builtin_amdgcn_mfma_f32_16x16x32_bf16(af[t][dy], bf, acc[t][ph], 0, 0, 0);
        }
      }
    // epilogue: relu each conv position, avg-pool, bf16, butterfly store
    const int b = b0 + bi;
#pragma unroll
    for (int t = 0; t < 4; ++t) {
      short pk[4];
#pragma unroll
      for (int r = 0; r < 4; ++r) {
        float po = 0.25f * (fmaxf(acc[t][0][r], 0.f) + fmaxf(acc[t][1][r], 0.f) +
                            fmaxf(acc[t][2][r], 0.f) + fmaxf(acc[t][3][r], 0.f));
        pk[r] = f2bf(po);
      }
      const int gip = (A_y * 2 + (t >> 1)) * (2 * G) + A_x * 2 + (t & 1);
      size_t dst = (((size_t)b * (4 * NB) + gip) * (SO * SO) + py * SO + px) * 16 + g4 * 4;
      *(short4*)&yout[dst] = make_short4(pk[0], pk[1], pk[2], pk[3]);
    }
  }
}

// ---------------- FT layer: per-block 16->4 contraction + real/imag ----------------
// Block = (64-n tile, 32-b tile). Wft row lives in registers; loop over 8 b per thread.
__global__ __launch_bounds__(256) void k_ft(
    const short* __restrict__ v, const float* __restrict__ Wft,
    const float* __restrict__ bft, float* __restrict__ out) {
  const int n = blockIdx.x * 64 + (threadIdx.x & 63);
  const int b0 = blockIdx.y * 32 + (threadIdx.x >> 6) * 8;
  float w[64];
  const float4* wp = (const float4*)(Wft + (size_t)n * 64);
#pragma unroll
  for (int j = 0; j < 16; ++j) {
    float4 t = wp[j];
    w[4 * j] = t.x; w[4 * j + 1] = t.y; w[4 * j + 2] = t.z; w[4 * j + 3] = t.w;
  }
  const float4 bq = *(const float4*)(bft + (size_t)n * 4);
#pragma unroll 2
  for (int bb = 0; bb < 8; ++bb) {
    const int b = b0 + bb;
    const short* vp = v + ((size_t)b * 4096 + n) * 16;
    s16x8 a0 = *(const s16x8*)vp;
    s16x8 a1 = *(const s16x8*)(vp + 8);
    float vv[16];
#pragma unroll
    for (int j = 0; j < 8; ++j) { vv[j] = bf2f(a0[j]); vv[8 + j] = bf2f(a1[j]); }
    float f0 = bq.x, f1 = bq.y, f2 = bq.z, f3 = bq.w;
#pragma unroll
    for (int j = 0; j < 16; ++j) {
      f0 += vv[j] * w[j];
      f1 += vv[j] * w[16 + j];
      f2 += vv[j] * w[32 + j];
      f3 += vv[j] * w[48 + j];
    }
    out[(size_t)b * 8192 + n] = f0 - f1;
    out[(size_t)b * 8192 + 4096 + n] = f2 - f3;
  }
}

extern "C" void kernel_launch(void* const* d_in, const int* in_sizes, int n_in,
                              void* d_out, int out_size, void* d_ws, size_t ws_size,
                              hipStream_t stream) {
  const float* x   = (const float*)d_in[0];
  const float* W0  = (const float*)d_in[1];
  const float* b0  = (const float*)d_in[2];
  const float* Wft = (const float*)d_in[3];
  const float* bft = (const float*)d_in[4];
  const float* W1 = (const float*)d_in[5];  const float* b1 = (const float*)d_in[6];
  const float* W2 = (const float*)d_in[7];  const float* b2 = (const float*)d_in[8];
  const float* W3 = (const float*)d_in[9];  const float* b3 = (const float*)d_in[10];
  const float* W4 = (const float*)d_in[11]; const float* b4 = (const float*)d_in[12];
  const float* W5 = (const float*)d_in[13]; const float* b5 = (const float*)d_in[14];

  short* buf0 = (short*)d_ws;                       // 16.7M bf16 = 33.5 MB
  short* buf1 = buf0 + (size_t)16777216;

  k_layer0<<<dim3(256, 4), 256, 0, stream>>>(x, W0, b0, buf0);
  // grid = (bc, gi, ph-chunk); consecutive blocks share gi -> weight L2 locality
  // L1: S=32, G=2,  1 img/block,  PH=4 -> grid (256, 4, 4), LDS 17.5 KB
  k_bconv<32, 2, 1, 4><<<dim3(256, 4, 4), 256, 0, stream>>>(buf0, W1, b1, buf1);
  // L2: S=16, G=4,  4 img/block,  PH=4 -> grid (64, 16, 2), LDS 27.6 KB
  k_bconv<16, 4, 4, 4><<<dim3(64, 16, 2), 256, 0, stream>>>(buf1, W2, b2, buf0);
  // L3: S=8,  G=8,  8 img/block,  PH=4 -> grid (32, 64, 1), LDS 28.7 KB
  k_bconv<8, 8, 8, 4><<<dim3(32, 64, 1), 256, 0, stream>>>(buf0, W3, b3, buf1);
  // L4: S=4,  G=16, 32 img/block, PH=2 -> grid (8, 256, 1), LDS 33.6 KB
  k_bconv<4, 16, 32, 2><<<dim3(8, 256, 1), 256, 0, stream>>>(buf1, W4, b4, buf0);
  // L5: S=2,  G=32, 128 img/block, PH=1 -> grid (2, 1024, 1), LDS 44.9 KB
  k_bconv<2, 32, 128, 1><<<dim3(2, 1024, 1), 256, 0, stream>>>(buf0, W5, b5, buf1);
  // FT: register-resident Wft, coalesced v/out
  k_ft<<<dim3(64, 8), 256, 0, stream>>>(buf1, Wft, bft, (float*)d_out);
}

// Round 7
// 233.389 us; speedup vs baseline: 11.0561x; 1.1548x over previous
//
#include <hip/hip_runtime.h>
#include <hip/hip_bf16.h>

// ButterFlyNet2D forward — round 7: LDS-free direct-MFMA conv layers.
// Intermediate layout after every layer: [B][group][y][x][16 ic] bf16, where
// "group" is the NEXT layer's group index (butterfly permute folded into store).
// d_ws: buf0 (33.5MB) | buf1 (33.5MB) | wbf (11.2MB bf16 A-frag-ordered weights).

typedef __attribute__((ext_vector_type(4))) float f32x4;
typedef __attribute__((ext_vector_type(8))) short s16x8;

__device__ __forceinline__ short f2bf(float f) {
  union { float f; unsigned u; } v; v.f = f;
  unsigned r = v.u + 0x7fff + ((v.u >> 16) & 1);   // RNE
  return (short)(r >> 16);
}
__device__ __forceinline__ float bf2f(short s) {
  union { unsigned u; float f; } v; v.u = ((unsigned)(unsigned short)s) << 16;
  return v.f;
}
constexpr int ilog2c(int v) { return v <= 1 ? 0 : 1 + ilog2c(v / 2); }

// Weight-buffer short offsets per layer (within wbf): E_l = 4^l * 4096 shorts.
#define WOFF1 0
#define WOFF2 16384
#define WOFF3 81920
#define WOFF4 344064
#define WOFF5 1392640
#define WTOT  5586944

// ---------------- Weight permute+convert: fp32 -> bf16 in A-fragment order ----------------
// dst idx within gi: i = (((t*2+dy)*4+g)*16+row)*8+j, k=8g+j=(dx*16+ic)
__global__ __launch_bounds__(256) void k_wconv(
    const float* __restrict__ W1, const float* __restrict__ W2,
    const float* __restrict__ W3, const float* __restrict__ W4,
    const float* __restrict__ W5, short* __restrict__ wbf) {
  const int idx = blockIdx.x * 256 + threadIdx.x;
  if (idx >= WTOT) return;
  const float* src;
  int local;
  if (idx < WOFF2)      { src = W1; local = idx; }
  else if (idx < WOFF3) { src = W2; local = idx - WOFF2; }
  else if (idx < WOFF4) { src = W3; local = idx - WOFF3; }
  else if (idx < WOFF5) { src = W4; local = idx - WOFF4; }
  else                  { src = W5; local = idx - WOFF5; }
  const int gi = local >> 12, i = local & 4095;
  const int j = i & 7, row = (i >> 3) & 15, g = (i >> 7) & 3, dy = (i >> 9) & 1, t = i >> 10;
  const int k = 8 * g + j, ic = k & 15, dx = k >> 4;
  wbf[idx] = f2bf(src[(size_t)gi * 4096 + ((t * 16 + row) * 16 + ic) * 4 + dy * 2 + dx]);
}

// ---------------- Layer 0: split -> conv(4->64,2x2) -> relu -> wrap-pad -> pool ----------------
// Output: [b][g=oc>>4][y 0..31][x 0..31][c=oc&15] bf16. LDS-staged coalesced stores.
__global__ __launch_bounds__(256) void k_layer0(
    const float* __restrict__ x, const float* __restrict__ W0,
    const float* __restrict__ b0, short* __restrict__ out) {
  constexpr int GS = 4112;
  __shared__ __align__(16) float xs[17 * 64];
  __shared__ __align__(16) short os[4 * GS];
  const int b = blockIdx.x, p0 = blockIdx.y * 8;
  const float* xb = x + (size_t)b * 4096;
  for (int i = threadIdx.x; i < 17 * 16; i += 256) {
    int lr = i >> 4, c4 = i & 15;
    ((float4*)xs)[i] = *(const float4*)(xb + ((2 * p0 + lr) & 63) * 64 + c4 * 4);
  }
  __syncthreads();
  const int oc = threadIdx.x & 63, wv = threadIdx.x >> 6;
  const int g = oc >> 4, c = oc & 15;
  float wp[2][2], wm[2][2];
#pragma unroll
  for (int kh = 0; kh < 2; ++kh)
#pragma unroll
    for (int kw = 0; kw < 2; ++kw) {
      wp[kh][kw] = W0[((oc * 4 + 0) * 2 + kh) * 2 + kw];
      wm[kh][kw] = W0[((oc * 4 + 1) * 2 + kh) * 2 + kw];
    }
  const float bias = b0[oc];
  for (int t = wv; t < 64; t += 4) {
    const int phl = t >> 3, c0 = (t & 7) * 8;
    const int lrA = 2 * phl;
    float vA[9], vB[9], vC[9];
#pragma unroll
    for (int j = 0; j < 8; ++j) {
      vA[j] = xs[lrA * 64 + c0 + j];
      vB[j] = xs[(lrA + 1) * 64 + c0 + j];
      vC[j] = xs[(lrA + 2) * 64 + c0 + j];
    }
    vA[8] = xs[lrA * 64 + ((c0 + 8) & 63)];
    vB[8] = xs[(lrA + 1) * 64 + ((c0 + 8) & 63)];
    vC[8] = xs[(lrA + 2) * 64 + ((c0 + 8) & 63)];
    float pA[9], mA[9], pB[9], mB[9], pC[9], mC[9];
#pragma unroll
    for (int j = 0; j < 9; ++j) {
      pA[j] = fmaxf(vA[j], 0.f); mA[j] = pA[j] - vA[j];
      pB[j] = fmaxf(vB[j], 0.f); mB[j] = pB[j] - vB[j];
      pC[j] = fmaxf(vC[j], 0.f); mC[j] = pC[j] - vC[j];
    }
    float sc0[8], sc1[8];
#pragma unroll
    for (int q = 0; q < 8; ++q) {
      sc0[q] = bias + wp[0][0] * pA[q] + wm[0][0] * mA[q] + wp[0][1] * pA[q + 1] + wm[0][1] * mA[q + 1]
                    + wp[1][0] * pB[q] + wm[1][0] * mB[q] + wp[1][1] * pB[q + 1] + wm[1][1] * mB[q + 1];
      sc1[q] = bias + wp[0][0] * pB[q] + wm[0][0] * mB[q] + wp[0][1] * pB[q + 1] + wm[0][1] * mB[q + 1]
                    + wp[1][0] * pC[q] + wm[1][0] * mC[q] + wp[1][1] * pC[q + 1] + wm[1][1] * mC[q + 1];
    }
#pragma unroll
    for (int p = 0; p < 4; ++p) {
      float po = 0.25f * (fmaxf(sc0[2 * p], 0.f) + fmaxf(sc0[2 * p + 1], 0.f) +
                          fmaxf(sc1[2 * p], 0.f) + fmaxf(sc1[2 * p + 1], 0.f));
      os[g * GS + (phl * 32 + c0 / 2 + p) * 16 + c] = f2bf(po);
    }
  }
  __syncthreads();
#pragma unroll
  for (int gg = 0; gg < 4; ++gg) {
    short* dst = out + ((size_t)b * 4 + gg) * 16384 + (size_t)p0 * 512;
    for (int i = threadIdx.x; i < 512; i += 256)
      *(float4*)&dst[i * 8] = *(const float4*)&os[gg * GS + i * 8];
  }
}

// ---------------- Direct MFMA recursion layer (no LDS, no barriers) ----------------
// Grouped conv 16->64 (2x2 circular) + bias + relu + pool + butterfly store.
// Wave handles ITW chunks of 16 pooled positions x 64 oc for one group gi.
// A-frags: 8x16B loads from pre-permuted wbf (L2-hit). B-frags: 6x16B direct global.
template <int S, int G, int ITW>
__global__ __launch_bounds__(256) void k_bconv(
    const short* __restrict__ yin, const short* __restrict__ wbf,
    const float* __restrict__ Bv, short* __restrict__ yout) {
  constexpr int NB = G * G;
  constexpr int SO = S / 2;
  constexpr int LOG_SO = ilog2c(SO);
  const int gi = blockIdx.y;
  const int lane = threadIdx.x & 63, wv = threadIdx.x >> 6;
  const int lp = lane & 15, g4 = lane >> 4;
  const int dxg = g4 >> 1, ich = g4 & 1;

  // A-frags: whole 64x64 weight matrix in 32 VGPR/lane
  const short* wl = wbf + (size_t)gi * 4096;
  s16x8 af[4][2];
#pragma unroll
  for (int t = 0; t < 4; ++t)
#pragma unroll
    for (int dy = 0; dy < 2; ++dy)
      af[t][dy] = *(const s16x8*)&wl[(((t * 2 + dy) * 4 + g4) * 16 + lp) * 8];
  f32x4 bv[4];
#pragma unroll
  for (int t = 0; t < 4; ++t)
    bv[t] = *(const f32x4*)&Bv[(size_t)gi * 64 + t * 16 + g4 * 4];

  const int A_y = gi / G, A_x = gi - A_y * G;
  const int chunk0 = (blockIdx.x * 4 + wv) * ITW;

#pragma unroll
  for (int it = 0; it < ITW; ++it) {
    const int pg = (chunk0 + it) * 16 + lp;
    const int px = pg & (SO - 1);
    const int py = (pg >> LOG_SO) & (SO - 1);
    const int bi = pg >> (2 * LOG_SO);
    const size_t base = ((size_t)bi * NB + gi) * (S * S * 16) + ich * 8;
    // 6 B-frags: rows 2py+{0,1,2}, cols 2px+dxg+{0,1} (wrapped)
    s16x8 bf[3][2];
#pragma unroll
    for (int rr = 0; rr < 3; ++rr) {
      const int r = (2 * py + rr) & (S - 1);
#pragma unroll
      for (int cc = 0; cc < 2; ++cc) {
        const int c = (2 * px + dxg + cc) & (S - 1);
        bf[rr][cc] = *(const s16x8*)&yin[base + (size_t)(r * S + c) * 16];
      }
    }
    f32x4 acc[4][4];
#pragma unroll
    for (int t = 0; t < 4; ++t)
#pragma unroll
      for (int ph = 0; ph < 4; ++ph) acc[t][ph] = bv[t];
#pragma unroll
    for (int phy = 0; phy < 2; ++phy)
#pragma unroll
      for (int phx = 0; phx < 2; ++phx) {
        const int ph = phy * 2 + phx;
#pragma unroll
        for (int dy = 0; dy < 2; ++dy) {
          s16x8 frag = bf[phy + dy][phx];
#pragma unroll
          for (int t = 0; t < 4; ++t)
            acc[t][ph] = __builtin_amdgcn_mfma_f32_16x16x32_bf16(af[t][dy], frag, acc[t][ph], 0, 0, 0);
        }
      }
    // epilogue: relu each conv position, avg-pool, bf16, butterfly store
#pragma unroll
    for (int t = 0; t < 4; ++t) {
      short pk[4];
#pragma unroll
      for (int r = 0; r < 4; ++r) {
        float po = 0.25f * (fmaxf(acc[t][0][r], 0.f) + fmaxf(acc[t][1][r], 0.f) +
                            fmaxf(acc[t][2][r], 0.f) + fmaxf(acc[t][3][r], 0.f));
        pk[r] = f2bf(po);
      }
      const int gip = (A_y * 2 + (t >> 1)) * (2 * G) + A_x * 2 + (t & 1);
      size_t dst = (((size_t)bi * (4 * NB) + gip) * (SO * SO) + py * SO + px) * 16 + g4 * 4;
      *(short4*)&yout[dst] = make_short4(pk[0], pk[1], pk[2], pk[3]);
    }
  }
}

// ---------------- FT layer: per-block 16->4 contraction + real/imag ----------------
__global__ __launch_bounds__(256) void k_ft(
    const short* __restrict__ v, const float* __restrict__ Wft,
    const float* __restrict__ bft, float* __restrict__ out) {
  const int n = blockIdx.x * 64 + (threadIdx.x & 63);
  const int b0 = blockIdx.y * 32 + (threadIdx.x >> 6) * 8;
  float w[64];
  const float4* wp = (const float4*)(Wft + (size_t)n * 64);
#pragma unroll
  for (int j = 0; j < 16; ++j) {
    float4 t = wp[j];
    w[4 * j] = t.x; w[4 * j + 1] = t.y; w[4 * j + 2] = t.z; w[4 * j + 3] = t.w;
  }
  const float4 bq = *(const float4*)(bft + (size_t)n * 4);
#pragma unroll 2
  for (int bb = 0; bb < 8; ++bb) {
    const int b = b0 + bb;
    const short* vp = v + ((size_t)b * 4096 + n) * 16;
    s16x8 a0 = *(const s16x8*)vp;
    s16x8 a1 = *(const s16x8*)(vp + 8);
    float vv[16];
#pragma unroll
    for (int j = 0; j < 8; ++j) { vv[j] = bf2f(a0[j]); vv[8 + j] = bf2f(a1[j]); }
    float f0 = bq.x, f1 = bq.y, f2 = bq.z, f3 = bq.w;
#pragma unroll
    for (int j = 0; j < 16; ++j) {
      f0 += vv[j] * w[j];
      f1 += vv[j] * w[16 + j];
      f2 += vv[j] * w[32 + j];
      f3 += vv[j] * w[48 + j];
    }
    out[(size_t)b * 8192 + n] = f0 - f1;
    out[(size_t)b * 8192 + 4096 + n] = f2 - f3;
  }
}

extern "C" void kernel_launch(void* const* d_in, const int* in_sizes, int n_in,
                              void* d_out, int out_size, void* d_ws, size_t ws_size,
                              hipStream_t stream) {
  const float* x   = (const float*)d_in[0];
  const float* W0  = (const float*)d_in[1];
  const float* b0  = (const float*)d_in[2];
  const float* Wft = (const float*)d_in[3];
  const float* bft = (const float*)d_in[4];
  const float* W1 = (const float*)d_in[5];  const float* b1 = (const float*)d_in[6];
  const float* W2 = (const float*)d_in[7];  const float* b2 = (const float*)d_in[8];
  const float* W3 = (const float*)d_in[9];  const float* b3 = (const float*)d_in[10];
  const float* W4 = (const float*)d_in[11]; const float* b4 = (const float*)d_in[12];
  const float* W5 = (const float*)d_in[13]; const float* b5 = (const float*)d_in[14];

  short* buf0 = (short*)d_ws;                       // 16.7M bf16 = 33.5 MB
  short* buf1 = buf0 + (size_t)16777216;
  short* wbf  = buf1 + (size_t)16777216;            // 11.2 MB permuted weights

  k_wconv<<<(WTOT + 255) / 256, 256, 0, stream>>>(W1, W2, W3, W4, W5, wbf);
  k_layer0<<<dim3(256, 4), 256, 0, stream>>>(x, W0, b0, buf0);
  // grid = (waves_per_gi/4/ITW, NB); ITW=2 -> 2048 blocks each layer
  k_bconv<32, 2, 2><<<dim3(512, 4), 256, 0, stream>>>(buf0, wbf + WOFF1, b1, buf1);
  k_bconv<16, 4, 2><<<dim3(128, 16), 256, 0, stream>>>(buf1, wbf + WOFF2, b2, buf0);
  k_bconv<8, 8, 2><<<dim3(32, 64), 256, 0, stream>>>(buf0, wbf + WOFF3, b3, buf1);
  k_bconv<4, 16, 2><<<dim3(8, 256), 256, 0, stream>>>(buf1, wbf + WOFF4, b4, buf0);
  k_bconv<2, 32, 2><<<dim3(2, 1024), 256, 0, stream>>>(buf0, wbf + WOFF5, b5, buf1);
  // FT: register-resident Wft, coalesced v/out
  k_ft<<<dim3(64, 8), 256, 0, stream>>>(buf1, Wft, bft, (float*)d_out);
}